// Round 15
// baseline (426.592 us; speedup 1.0000x reference)
//
#include <hip/hip_runtime.h>
#include <hip/hip_bf16.h>
#include <stdint.h>

// ---------------------------------------------------------------------------
// LSTM cell, fused as one bf16 MFMA GEMM:
//   A  = [input | hidden]            : [16384][2048]  (bf16, packed in ws)
//   W  = [Wx[g] | Wh[g]] per gate g  : [4096][2048]   (bf16, packed in ws, [N][K])
//   pre[g][b][s] = sum_k A[b][k] * W[g*1024+s][k] + bias[g][s]
//
// Round 15 = r13 champion (GEMM 281us, MfmaUtil 46%) + ONE change:
// SPLIT double-buffering -- A (HBM stream, ~600-900cyc) double-buffered with
// a full tile of slack; W (L2-resident via col-major XCD remap, ~250-400cyc)
// single-buffered. LDS = 2x16KB A + 32KB W = 64KB -> still 2 blocks/CU.
//   * per tile: STAGE_A(t+1) issued BEFORE the wait; counted vmcnt(2)
//     retires {A(t)x2, W(t)x4}, leaves A(t+1)x2 in flight across both
//     barriers; STAGE_W(t+1) after barrier-2 (WAR-safe: all waves done
//     reading sW).
//   * exposed drain/tile: ~700cyc (max over A-HBM) -> ~250-300cyc (W-L2).
//   * same 32 iters / 64 barriers, same verified swizzle (0 conflicts),
//     same wave tile 64r x 16s x 4g (acc[4][4], 0.5 reads/MFMA).
// r14 lesson: BM=64 blocks doubled staged-W per FLOP -> regression; BM=128
// restored.
// ---------------------------------------------------------------------------

typedef short bf16x8 __attribute__((ext_vector_type(8)));
typedef float f32x4 __attribute__((ext_vector_type(4)));

#define B_ROWS 16384
#define D_K 2048

__device__ __forceinline__ unsigned short f2bf(float f) {
    unsigned u = __builtin_bit_cast(unsigned, f);
    u += 0x7FFFu + ((u >> 16) & 1u);   // round-to-nearest-even
    return (unsigned short)(u >> 16);
}

__device__ __forceinline__ float sigf(float x) { return 1.0f / (1.0f + __expf(-x)); }
__device__ __forceinline__ float tanhfast(float x) { return 2.0f / (1.0f + __expf(-2.0f * x)) - 1.0f; }

// global -> LDS direct copy, 16B per lane; LDS dest wave-uniform base + lane*16.
#define GLD16(gp, lp)                                                          \
    __builtin_amdgcn_global_load_lds(                                          \
        (const __attribute__((address_space(1))) unsigned int*)(gp),           \
        (__attribute__((address_space(3))) unsigned int*)(lp), 16, 0, 0)

#define FENCE() asm volatile("" ::: "memory")

// --------------------------- pack kernels ----------------------------------

__global__ void pack_A_kernel(const float* __restrict__ x,
                              const float* __restrict__ h,
                              unsigned short* __restrict__ A) {
    const int total = B_ROWS * (D_K / 4);          // vec4 units, 512 per row
    for (int v = blockIdx.x * blockDim.x + threadIdx.x; v < total;
         v += gridDim.x * blockDim.x) {
        const int b = v >> 9;
        const int k0 = (v & 511) << 2;
        const float* src = (k0 < 1024) ? (x + (size_t)b * 1024 + k0)
                                       : (h + (size_t)b * 1024 + (k0 - 1024));
        float4 f = *(const float4*)src;
        unsigned p0 = (unsigned)f2bf(f.x) | ((unsigned)f2bf(f.y) << 16);
        unsigned p1 = (unsigned)f2bf(f.z) | ((unsigned)f2bf(f.w) << 16);
        uint2 o; o.x = p0; o.y = p1;
        *(uint2*)(A + (size_t)v * 4) = o;
    }
}

__global__ void pack_W_kernel(const float* __restrict__ Wx,
                              const float* __restrict__ Wh,
                              unsigned short* __restrict__ W) {
    const int total = 4096 * (D_K / 4);
    for (int v = blockIdx.x * blockDim.x + threadIdx.x; v < total;
         v += gridDim.x * blockDim.x) {
        const int n = v >> 9;                       // n = g*1024 + s
        const int k0 = (v & 511) << 2;
        const float* src = (k0 < 1024) ? (Wx + (size_t)n * 1024 + k0)
                                       : (Wh + (size_t)n * 1024 + (k0 - 1024));
        float4 f = *(const float4*)src;
        unsigned p0 = (unsigned)f2bf(f.x) | ((unsigned)f2bf(f.y) << 16);
        unsigned p1 = (unsigned)f2bf(f.z) | ((unsigned)f2bf(f.w) << 16);
        uint2 o; o.x = p0; o.y = p1;
        *(uint2*)(W + (size_t)v * 4) = o;
    }
}

__global__ void pack_bias_kernel(const float* __restrict__ bx,
                                 const float* __restrict__ bh,
                                 float* __restrict__ bias) {
    int i = blockIdx.x * blockDim.x + threadIdx.x;
    if (i < 4096) bias[i] = bx[i] + bh[i];
}

// --------------------------- fused GEMM ------------------------------------
// Tile: BM=128 rows (b), BN=64 cols (s) x 4 gates, BK=64, 32 K-tiles.
// 512 threads = 8 waves 2M x 4N: wave = 64r x 16s x 4g -> acc[4][4] f32x4.
// LDS: sA = 2 x 16KB (double-buffered), sW = 32KB (single). Chunk = 1KB =
// 8 rows x 64 elems, column pre-swizzled on the global side (verified).

__global__ __launch_bounds__(512, 2) void lstm_gemm_kernel(
    const unsigned short* __restrict__ A,     // [16384][2048]
    const unsigned short* __restrict__ W,     // [4096][2048]
    const float* __restrict__ bias,           // [4096]
    const float* __restrict__ cell,           // [16384][1024]
    float* __restrict__ out) {                // new_c then h, each [16384][1024]
    __shared__ __align__(16) unsigned short sA[2][8192];   // 2 x 16 KB
    __shared__ __align__(16) unsigned short sW[16384];     // 32 KB

    // XCD-aware remap: 2048 blocks, 8 XCDs, 256 blocks/XCD (bijective).
    const int bid = blockIdx.x;
    const int wg = (bid & 7) * 256 + (bid >> 3);
    const int brow = (wg >> 4) << 7;          // row stripe * 128
    const int bcol = (wg & 15) << 6;          // col tile * 64

    const int tid = threadIdx.x;
    const int wid = tid >> 6;                 // 0..7
    const int lane = tid & 63;
    const int wr = wid >> 2;                  // 0..1: rows wr*64..+64
    const int wc = wid & 3;                   // 0..3: s-cols wc*16..+16
    const int lr = lane & 15, lg = lane >> 4;
    const int l8 = lane >> 3;                 // row within a 1KB staging chunk
    // PRE-SWIZZLED global column (verified: 0 conflicts): linear LDS slot
    // (lane&7) receives global col ((lane&7)^l8)*8.
    const int lcol = (((lane & 7) ^ l8) << 3);

    f32x4 acc[4][4];
#pragma unroll
    for (int g = 0; g < 4; ++g)
#pragma unroll
        for (int m = 0; m < 4; ++m) acc[g][m] = (f32x4){0.f, 0.f, 0.f, 0.f};

    // staging sources: wave stages 2 A-chunks + 4 W-chunks per tile
    const unsigned short* gpA[2];
#pragma unroll
    for (int i = 0; i < 2; ++i) {
        const int c = wid * 2 + i;            // 16 A chunks: rows c*8..c*8+7
        gpA[i] = A + (size_t)(brow + c * 8 + l8) * D_K + lcol;
    }
    const unsigned short* gpW[4];
#pragma unroll
    for (int i = 0; i < 4; ++i) {
        const int cw = wid * 4 + i;           // 32 W chunks: gate cw>>3, rows (cw&7)*8..
        gpW[i] = W + (size_t)((cw >> 3) * 1024 + bcol + (cw & 7) * 8 + l8) * D_K + lcol;
    }

#define STAGE_A(buf, kt)                                                       \
    do {                                                                       \
        GLD16(gpA[0] + (kt), (char*)sA[buf] + (wid * 2) * 1024);               \
        GLD16(gpA[1] + (kt), (char*)sA[buf] + (wid * 2 + 1) * 1024);           \
    } while (0)

#define STAGE_W(kt)                                                            \
    do {                                                                       \
        _Pragma("unroll")                                                      \
        for (int _i = 0; _i < 4; ++_i)                                         \
            GLD16(gpW[_i] + (kt), (char*)sW + (wid * 4 + _i) * 1024);          \
    } while (0)

#define COMPUTE(buf)                                                           \
    do {                                                                       \
        const unsigned short* _sa = sA[buf];                                   \
        _Pragma("unroll")                                                      \
        for (int kk = 0; kk < 2; ++kk) {                                       \
            const int swk = (kk * 32 + lg * 8) ^ ((lr & 7) << 3);              \
            bf16x8 a[4], w[4];                                                 \
            _Pragma("unroll")                                                  \
            for (int m = 0; m < 4; ++m)                                        \
                a[m] = *(const bf16x8*)&_sa[(wr * 64 + m * 16 + lr) * 64 + swk]; \
            _Pragma("unroll")                                                  \
            for (int g = 0; g < 4; ++g)                                        \
                w[g] = *(const bf16x8*)&sW[(g * 64 + wc * 16 + lr) * 64 + swk]; \
            __builtin_amdgcn_s_setprio(1);                                     \
            _Pragma("unroll")                                                  \
            for (int g = 0; g < 4; ++g) {                                      \
                _Pragma("unroll")                                              \
                for (int m = 0; m < 4; ++m)                                    \
                    acc[g][m] = __builtin_amdgcn_mfma_f32_16x16x32_bf16(       \
                        a[m], w[g], acc[g][m], 0, 0, 0);                       \
            }                                                                  \
            __builtin_amdgcn_s_setprio(0);                                     \
        }                                                                      \
    } while (0)

    // prologue: queue (oldest first) = [A0 x2, W0 x4]
    STAGE_A(0, 0);
    STAGE_W(0);

    // 31 pipelined iterations + peeled tail.
    // Per iter t, queue at the wait: [A(t) x2, W(t) x4, A(t+1) x2];
    // vmcnt(2) retires {A(t), W(t)}, leaves A(t+1) in flight.
    for (int t = 0; t < 31; ++t) {
        STAGE_A((t + 1) & 1, (t + 1) * 64);
        asm volatile("s_waitcnt vmcnt(2)" ::: "memory");
        __builtin_amdgcn_s_barrier();
        FENCE();
        COMPUTE(t & 1);
        FENCE();
        __builtin_amdgcn_s_barrier();     // all waves done reading sW
        FENCE();
        STAGE_W((t + 1) * 64);            // refill single W buffer
    }
    // tail: tile 31 (buf 1); queue = [A31 x2, W31 x4]
    asm volatile("s_waitcnt vmcnt(0)" ::: "memory");
    __builtin_amdgcn_s_barrier();
    FENCE();
    COMPUTE(1);

#undef STAGE_A
#undef STAGE_W
#undef COMPUTE

    // fused epilogue: C/D layout col = lane&15, row = (lane>>4)*4 + reg
    float bv[4];
#pragma unroll
    for (int g = 0; g < 4; ++g) bv[g] = bias[(g << 10) + bcol + wc * 16 + lr];

    float* outc = out;
    float* outh = out + (size_t)B_ROWS * 1024;
#pragma unroll
    for (int m = 0; m < 4; ++m) {
#pragma unroll
        for (int r = 0; r < 4; ++r) {
            const int b = brow + wr * 64 + m * 16 + lg * 4 + r;
            const size_t idx = (size_t)b * 1024 + bcol + wc * 16 + lr;
            float pf = acc[0][m][r] + bv[0];
            float pi = acc[1][m][r] + bv[1];
            float pc = acc[2][m][r] + bv[2];
            float po = acc[3][m][r] + bv[3];
            float cl = cell[idx];
            float nc = cl * sigf(pf) + sigf(pi) * tanhfast(pc);
            outc[idx] = nc;
            outh[idx] = tanhfast(nc) * sigf(po);
        }
    }
}

// ------------------- fp32 fallback (ws too small; slow but correct) --------

__global__ void lstm_naive_kernel(const float* __restrict__ x,
                                  const float* __restrict__ cell,
                                  const float* __restrict__ h,
                                  const float* __restrict__ Wx,
                                  const float* __restrict__ bx,
                                  const float* __restrict__ Wh,
                                  const float* __restrict__ bh,
                                  float* __restrict__ out) {
    int idx = blockIdx.x * blockDim.x + threadIdx.x;
    if (idx >= B_ROWS * 1024) return;
    int b = idx >> 10, s = idx & 1023;
    const float* xr = x + (size_t)b * 1024;
    const float* hr = h + (size_t)b * 1024;
    float pre[4];
#pragma unroll
    for (int g = 0; g < 4; ++g) {
        float acc = bx[(g << 10) + s] + bh[(g << 10) + s];
        const float* wx = Wx + ((size_t)(g << 10) + s) * 1024;
        const float* wh = Wh + ((size_t)(g << 10) + s) * 1024;
        for (int k = 0; k < 1024; ++k) acc += xr[k] * wx[k] + hr[k] * wh[k];
        pre[g] = acc;
    }
    float nc = cell[idx] * sigf(pre[0]) + sigf(pre[1]) * tanhfast(pre[2]);
    out[idx] = nc;
    out[(size_t)B_ROWS * 1024 + idx] = tanhfast(nc) * sigf(pre[3]);
}

// ---------------------------------------------------------------------------

extern "C" void kernel_launch(void* const* d_in, const int* in_sizes, int n_in,
                              void* d_out, int out_size, void* d_ws, size_t ws_size,
                              hipStream_t stream) {
    const float* x    = (const float*)d_in[0];
    const float* cell = (const float*)d_in[1];
    const float* hid  = (const float*)d_in[2];
    const float* Wx   = (const float*)d_in[3];
    const float* bx   = (const float*)d_in[4];
    const float* Wh   = (const float*)d_in[5];
    const float* bh   = (const float*)d_in[6];
    float* out = (float*)d_out;

    const size_t szA = (size_t)B_ROWS * D_K * 2;    // 64 MB
    const size_t szW = (size_t)4096 * D_K * 2;      // 16 MB
    const size_t szB = 4096 * 4;
    if (ws_size < szA + szW + szB) {
        lstm_naive_kernel<<<(B_ROWS * 1024) / 256, 256, 0, stream>>>(
            x, cell, hid, Wx, bx, Wh, bh, out);
        return;
    }

    unsigned short* Ab = (unsigned short*)d_ws;
    unsigned short* Wb = (unsigned short*)((char*)d_ws + szA);
    float* bias = (float*)((char*)d_ws + szA + szW);

    pack_A_kernel<<<8192, 256, 0, stream>>>(x, hid, Ab);
    pack_W_kernel<<<2048, 256, 0, stream>>>(Wx, Wh, Wb);
    pack_bias_kernel<<<16, 256, 0, stream>>>(bx, bh, bias);

    lstm_gemm_kernel<<<2048, 512, 0, stream>>>(Ab, Wb, bias, cell, out);
}

// Round 16
// 311.464 us; speedup vs baseline: 1.3696x; 1.3696x over previous
//
#include <hip/hip_runtime.h>
#include <hip/hip_bf16.h>
#include <stdint.h>

// ---------------------------------------------------------------------------
// LSTM cell, fused as one bf16 MFMA GEMM:
//   A  = [input | hidden]            : [16384][2048]  (bf16, packed in ws)
//   W  = [Wx[g] | Wh[g]] per gate g  : [4096][2048]   (bf16, packed in ws, [N][K])
//   pre[g][b][s] = sum_k A[b][k] * W[g*1024+s][k] + bias[g][s]
//
// Round 16 = r13 champion GEMM verbatim (281us, 982 TF, MfmaUtil 46%,
// conflicts 0) + ONE change outside the GEMM: the three pack kernels are
// merged into a single grid-stride dispatch (region-split by flat index),
// removing two launch gaps (~31us pack tail -> ~28us).
//
// Structural search summary (r6..r15): {single-buffer 48KB, 2 blk/CU,
// wave 64r x 16s x 4g (0.5 reads/MFMA), GLD16 DMA, vmcnt(0)+syncthreads,
// verified XOR swizzle, XCD remap} beat every pipelining variant:
//   r7 coarse dbuf 305us / r8 8-phase 305 / r9 4-deep ring 309 /
//   r10 ring x 2blk 345 / r14 4 small blk 397 / r15 split-buffer 450.
// LDS residency threshold measured: 48KB -> 2 blk/CU; >=64KB -> 1 blk/CU.
// ---------------------------------------------------------------------------

typedef short bf16x8 __attribute__((ext_vector_type(8)));
typedef float f32x4 __attribute__((ext_vector_type(4)));

#define B_ROWS 16384
#define D_K 2048

__device__ __forceinline__ unsigned short f2bf(float f) {
    unsigned u = __builtin_bit_cast(unsigned, f);
    u += 0x7FFFu + ((u >> 16) & 1u);   // round-to-nearest-even
    return (unsigned short)(u >> 16);
}

__device__ __forceinline__ float sigf(float x) { return 1.0f / (1.0f + __expf(-x)); }
__device__ __forceinline__ float tanhfast(float x) { return 2.0f / (1.0f + __expf(-2.0f * x)) - 1.0f; }

// global -> LDS direct copy, 16B per lane; LDS dest wave-uniform base + lane*16.
#define GLD16(gp, lp)                                                          \
    __builtin_amdgcn_global_load_lds(                                          \
        (const __attribute__((address_space(1))) unsigned int*)(gp),           \
        (__attribute__((address_space(3))) unsigned int*)(lp), 16, 0, 0)

// --------------------------- merged pack kernel ----------------------------
// Region 0: A vec4 units [0, 16384*512)        -- [input | hidden] -> bf16
// Region 1: W vec4 units [.., +4096*512)       -- [Wx[g] | Wh[g]]  -> bf16
// Region 2: bias [.., +4096)                   -- bx + bh          -> f32

__global__ void pack_all_kernel(const float* __restrict__ x,
                                const float* __restrict__ h,
                                const float* __restrict__ Wx,
                                const float* __restrict__ Wh,
                                const float* __restrict__ bx,
                                const float* __restrict__ bh,
                                unsigned short* __restrict__ A,
                                unsigned short* __restrict__ W,
                                float* __restrict__ bias) {
    const int totalA = B_ROWS * (D_K / 4);         // 8,388,608
    const int totalW = 4096 * (D_K / 4);           // 2,097,152
    const int total = totalA + totalW + 4096;
    for (int v = blockIdx.x * blockDim.x + threadIdx.x; v < total;
         v += gridDim.x * blockDim.x) {
        if (v < totalA) {
            const int b = v >> 9;
            const int k0 = (v & 511) << 2;
            const float* src = (k0 < 1024) ? (x + (size_t)b * 1024 + k0)
                                           : (h + (size_t)b * 1024 + (k0 - 1024));
            float4 f = *(const float4*)src;
            unsigned p0 = (unsigned)f2bf(f.x) | ((unsigned)f2bf(f.y) << 16);
            unsigned p1 = (unsigned)f2bf(f.z) | ((unsigned)f2bf(f.w) << 16);
            uint2 o; o.x = p0; o.y = p1;
            *(uint2*)(A + (size_t)v * 4) = o;
        } else if (v < totalA + totalW) {
            const int u = v - totalA;
            const int n = u >> 9;                  // n = g*1024 + s
            const int k0 = (u & 511) << 2;
            const float* src = (k0 < 1024) ? (Wx + (size_t)n * 1024 + k0)
                                           : (Wh + (size_t)n * 1024 + (k0 - 1024));
            float4 f = *(const float4*)src;
            unsigned p0 = (unsigned)f2bf(f.x) | ((unsigned)f2bf(f.y) << 16);
            unsigned p1 = (unsigned)f2bf(f.z) | ((unsigned)f2bf(f.w) << 16);
            uint2 o; o.x = p0; o.y = p1;
            *(uint2*)(W + (size_t)u * 4) = o;
        } else {
            const int i = v - totalA - totalW;
            bias[i] = bx[i] + bh[i];
        }
    }
}

// --------------------------- fused GEMM (r13 verbatim) ---------------------
// Tile: BM=128 rows (b), BN=64 cols (s) x 4 gates, BK=64.
// 512 threads = 8 waves 2M x 4N: wave = 64r x 16s x 4g -> acc[4][4] f32x4.

__global__ __launch_bounds__(512, 2) void lstm_gemm_kernel(
    const unsigned short* __restrict__ A,     // [16384][2048]
    const unsigned short* __restrict__ W,     // [4096][2048]
    const float* __restrict__ bias,           // [4096]
    const float* __restrict__ cell,           // [16384][1024]
    float* __restrict__ out) {                // new_c then h, each [16384][1024]
    // 48 chunks of 1KB; chunk c holds 8 rows x 64 elems (A: 0..15, W: 16..47)
    __shared__ __align__(16) unsigned short smem[24576];

    // XCD-aware remap: 2048 blocks, 8 XCDs, 256 blocks/XCD (bijective).
    const int bid = blockIdx.x;
    const int wg = (bid & 7) * 256 + (bid >> 3);
    const int brow = (wg >> 4) << 7;          // row stripe * 128
    const int bcol = (wg & 15) << 6;          // col tile * 64

    const int tid = threadIdx.x;
    const int wid = tid >> 6;                 // 0..7
    const int lane = tid & 63;
    const int wr = wid >> 2;                  // 0..1: rows wr*64..+64
    const int wc = wid & 3;                   // 0..3: s-cols wc*16..+16
    const int lr = lane & 15, lg = lane >> 4;
    const int l8 = lane >> 3;                 // row within a 1KB staging chunk
    // PRE-SWIZZLED global column (verified: 0 conflicts): linear LDS slot
    // (lane&7) receives global col ((lane&7)^l8)*8.
    const int lcol = (((lane & 7) ^ l8) << 3);

    f32x4 acc[4][4];
#pragma unroll
    for (int g = 0; g < 4; ++g)
#pragma unroll
        for (int m = 0; m < 4; ++m) acc[g][m] = (f32x4){0.f, 0.f, 0.f, 0.f};

    // staging sources: wave w owns chunks w*6..w*6+5 (per-lane addresses)
    const unsigned short* gp[6];
#pragma unroll
    for (int i = 0; i < 6; ++i) {
        const int c = wid * 6 + i;
        if (c < 16) {
            gp[i] = A + (size_t)(brow + c * 8 + l8) * D_K + lcol;
        } else {
            const int cw = c - 16;
            gp[i] = W + (size_t)((cw >> 3) * 1024 + bcol + (cw & 7) * 8 + l8) * D_K + lcol;
        }
    }

    for (int kt = 0; kt < D_K; kt += 64) {
        // direct global->LDS DMA, no staging registers
#pragma unroll
        for (int i = 0; i < 6; ++i)
            GLD16(gp[i] + kt, (char*)smem + (wid * 6 + i) * 1024);
        asm volatile("s_waitcnt vmcnt(0)" ::: "memory");
        __syncthreads();

#pragma unroll
        for (int kk = 0; kk < 2; ++kk) {
            // swizzled k-column (elems); fragment row&7 == lr&7 everywhere
            const int swk = (kk * 32 + lg * 8) ^ ((lr & 7) << 3);
            bf16x8 a[4], w[4];
#pragma unroll
            for (int m = 0; m < 4; ++m)
                a[m] = *(const bf16x8*)&smem[(wr * 64 + m * 16 + lr) * 64 + swk];
#pragma unroll
            for (int g = 0; g < 4; ++g)
                w[g] = *(const bf16x8*)&smem[8192 + (g * 64 + wc * 16 + lr) * 64 + swk];
            __builtin_amdgcn_s_setprio(1);
#pragma unroll
            for (int g = 0; g < 4; ++g) {
#pragma unroll
                for (int m = 0; m < 4; ++m)
                    acc[g][m] = __builtin_amdgcn_mfma_f32_16x16x32_bf16(
                        a[m], w[g], acc[g][m], 0, 0, 0);
            }
            __builtin_amdgcn_s_setprio(0);
        }
        __syncthreads();
    }

    // fused epilogue: C/D layout col = lane&15, row = (lane>>4)*4 + reg
    float bv[4];
#pragma unroll
    for (int g = 0; g < 4; ++g) bv[g] = bias[(g << 10) + bcol + wc * 16 + lr];

    float* outc = out;
    float* outh = out + (size_t)B_ROWS * 1024;
#pragma unroll
    for (int m = 0; m < 4; ++m) {
#pragma unroll
        for (int r = 0; r < 4; ++r) {
            const int b = brow + wr * 64 + m * 16 + lg * 4 + r;
            const size_t idx = (size_t)b * 1024 + bcol + wc * 16 + lr;
            float pf = acc[0][m][r] + bv[0];
            float pi = acc[1][m][r] + bv[1];
            float pc = acc[2][m][r] + bv[2];
            float po = acc[3][m][r] + bv[3];
            float cl = cell[idx];
            float nc = cl * sigf(pf) + sigf(pi) * tanhfast(pc);
            outc[idx] = nc;
            outh[idx] = tanhfast(nc) * sigf(po);
        }
    }
}

// ------------------- fp32 fallback (ws too small; slow but correct) --------

__global__ void lstm_naive_kernel(const float* __restrict__ x,
                                  const float* __restrict__ cell,
                                  const float* __restrict__ h,
                                  const float* __restrict__ Wx,
                                  const float* __restrict__ bx,
                                  const float* __restrict__ Wh,
                                  const float* __restrict__ bh,
                                  float* __restrict__ out) {
    int idx = blockIdx.x * blockDim.x + threadIdx.x;
    if (idx >= B_ROWS * 1024) return;
    int b = idx >> 10, s = idx & 1023;
    const float* xr = x + (size_t)b * 1024;
    const float* hr = h + (size_t)b * 1024;
    float pre[4];
#pragma unroll
    for (int g = 0; g < 4; ++g) {
        float acc = bx[(g << 10) + s] + bh[(g << 10) + s];
        const float* wx = Wx + ((size_t)(g << 10) + s) * 1024;
        const float* wh = Wh + ((size_t)(g << 10) + s) * 1024;
        for (int k = 0; k < 1024; ++k) acc += xr[k] * wx[k] + hr[k] * wh[k];
        pre[g] = acc;
    }
    float nc = cell[idx] * sigf(pre[0]) + sigf(pre[1]) * tanhfast(pre[2]);
    out[idx] = nc;
    out[(size_t)B_ROWS * 1024 + idx] = tanhfast(nc) * sigf(pre[3]);
}

// ---------------------------------------------------------------------------

extern "C" void kernel_launch(void* const* d_in, const int* in_sizes, int n_in,
                              void* d_out, int out_size, void* d_ws, size_t ws_size,
                              hipStream_t stream) {
    const float* x    = (const float*)d_in[0];
    const float* cell = (const float*)d_in[1];
    const float* hid  = (const float*)d_in[2];
    const float* Wx   = (const float*)d_in[3];
    const float* bx   = (const float*)d_in[4];
    const float* Wh   = (const float*)d_in[5];
    const float* bh   = (const float*)d_in[6];
    float* out = (float*)d_out;

    const size_t szA = (size_t)B_ROWS * D_K * 2;    // 64 MB
    const size_t szW = (size_t)4096 * D_K * 2;      // 16 MB
    const size_t szB = 4096 * 4;
    if (ws_size < szA + szW + szB) {
        lstm_naive_kernel<<<(B_ROWS * 1024) / 256, 256, 0, stream>>>(
            x, cell, hid, Wx, bx, Wh, bh, out);
        return;
    }

    unsigned short* Ab = (unsigned short*)d_ws;
    unsigned short* Wb = (unsigned short*)((char*)d_ws + szA);
    float* bias = (float*)((char*)d_ws + szA + szW);

    pack_all_kernel<<<8192, 256, 0, stream>>>(x, hid, Wx, Wh, bx, bh,
                                              Ab, Wb, bias);

    lstm_gemm_kernel<<<2048, 512, 0, stream>>>(Ab, Wb, bias, cell, out);
}